// Round 8
// baseline (8044.826 us; speedup 1.0000x reference)
//
#include <hip/hip_runtime.h>
#include <hip/hip_fp16.h>

#define N_NODES 20000
#define N_EDGES 320000
#define BATCH   64
#define N_IN    128
#define N_OUT   256
#define CAP     64
#define ITERS   150
#define LEAK    0.01f

#define CNT_MASK 0x3FFFFFFF
#define FLAG_BIT (1 << 30)

#define NBLOCKS    1024
#define NTHREADS   256
#define NPW        5                 // nodes per wave; 4096 waves * 5 = 20480
#define CTRS       64                // distributed barrier counters
#define CTR_STRIDE 32                // ints -> 128B apart (no false sharing)

#define AT_LD(p)    __hip_atomic_load((p), __ATOMIC_RELAXED, __HIP_MEMORY_SCOPE_AGENT)
#define AT_ADD(p,v) __hip_atomic_fetch_add((p),(v),__ATOMIC_RELAXED,__HIP_MEMORY_SCOPE_AGENT)
#define AT_ST(p,v)  __hip_atomic_store((p),(v),__ATOMIC_RELAXED,__HIP_MEMORY_SCOPE_AGENT)

// ---------------------------------------------------------------------------
// setup: h0 = 0, cnt = 0, meta = 0, barrier state = 0.
// (bin needs no init: only rows fully written by the scatter are ever read.)
// ---------------------------------------------------------------------------
__global__ void setup_kernel(uint2* __restrict__ h0, int* __restrict__ cnt,
                             unsigned* __restrict__ um, unsigned* __restrict__ um2,
                             int* __restrict__ bar) {
    int idx = blockIdx.x * blockDim.x + threadIdx.x;
    int stride = gridDim.x * blockDim.x;
    for (int i = idx; i < N_NODES * 16; i += stride) h0[i] = make_uint2(0u, 0u);
    for (int i = idx; i < N_NODES * 32; i += stride) { um[i] = 0u; um2[i] = 0u; }
    for (int i = idx; i < N_NODES; i += stride) cnt[i] = 0;
    for (int i = idx; i < CTRS * CTR_STRIDE + CTR_STRIDE; i += stride) bar[i] = 0;
}

// ---------------------------------------------------------------------------
// input scatter: bin[in_idx[i]][b] = bias + in_w[i]*x[b][i], last-wins.
// Tags the node (bit 30 of cnt) so the step reads bin only for these rows.
// ---------------------------------------------------------------------------
__global__ void input_scatter_kernel(float* __restrict__ bin,
                                     const float* __restrict__ x,
                                     const float* __restrict__ in_w,
                                     const int* __restrict__ in_idx,
                                     const float* __restrict__ biases,
                                     int* __restrict__ cnt) {
    int i = blockIdx.x;
    int b = threadIdx.x;
    int node = in_idx[i];
    if (b == 0) atomicOr(&cnt[node], FLAG_BIT);
    for (int j = i + 1; j < N_IN; j++)
        if (in_idx[j] == node) return;
    bin[node * BATCH + b] = biases[node] + in_w[i] * x[b * N_IN + i];
}

// ---------------------------------------------------------------------------
// COO -> compressed permuted ELL. Slot value = (fp16(w) << 16) | u16(col).
// Slots 0..31 pack into um[node][32] so lane-group eg's 8 slots (s == eg mod 4)
// are 2 contiguous uint4; slots 32..63 (P(c>32) ~ 1e-4) go to um2 likewise.
// Zeroed slots decode to col 0 / w 0 -> guard-free.
// ---------------------------------------------------------------------------
__global__ void ell_build_kernel(const int* __restrict__ rows,
                                 const int* __restrict__ cols,
                                 const float* __restrict__ rec_w,
                                 unsigned* __restrict__ um,
                                 unsigned* __restrict__ um2,
                                 int* __restrict__ cnt) {
    int e = blockIdx.x * blockDim.x + threadIdx.x;
    if (e >= N_EDGES) return;
    int r = rows[e];
    int s = atomicAdd(&cnt[r], 1) & CNT_MASK;
    if (s < CAP) {
        unsigned v = ((unsigned)__half_as_ushort(__float2half(rec_w[e])) << 16)
                   | (unsigned)cols[e];
        if (s < 32) {
            um[r * 32 + ((s & 3) << 3) + (s >> 2)] = v;
        } else {
            int s2 = s - 32;
            um2[r * 32 + ((s2 & 3) << 3) + (s2 >> 2)] = v;
        }
    }
}

// ---------------------------------------------------------------------------
// per-node SpMV + activation body. Lane = eg*16+li: group eg handles slots
// == eg (mod 4); li spans the batch as uint2 (4 fp16). 8 independent gathers.
// ---------------------------------------------------------------------------
#define ACC4(g, w)                                                                       \
    a0 = fmaf(w, __half2float(__ushort_as_half((unsigned short)((g).x & 0xFFFF))), a0);  \
    a1 = fmaf(w, __half2float(__ushort_as_half((unsigned short)((g).x >> 16))),    a1);  \
    a2 = fmaf(w, __half2float(__ushort_as_half((unsigned short)((g).y & 0xFFFF))), a2);  \
    a3 = fmaf(w, __half2float(__ushort_as_half((unsigned short)((g).y >> 16))),    a3);

#define GATHER8(M0, M1)                                                  \
    {                                                                    \
        uint2 g0 = hv[((M0.x & 0xFFFFu) << 4) + li];                     \
        uint2 g1 = hv[((M0.y & 0xFFFFu) << 4) + li];                     \
        uint2 g2 = hv[((M0.z & 0xFFFFu) << 4) + li];                     \
        uint2 g3 = hv[((M0.w & 0xFFFFu) << 4) + li];                     \
        uint2 g4 = hv[((M1.x & 0xFFFFu) << 4) + li];                     \
        uint2 g5 = hv[((M1.y & 0xFFFFu) << 4) + li];                     \
        uint2 g6 = hv[((M1.z & 0xFFFFu) << 4) + li];                     \
        uint2 g7 = hv[((M1.w & 0xFFFFu) << 4) + li];                     \
        ACC4(g0, __half2float(__ushort_as_half((unsigned short)(M0.x >> 16)))); \
        ACC4(g1, __half2float(__ushort_as_half((unsigned short)(M0.y >> 16)))); \
        ACC4(g2, __half2float(__ushort_as_half((unsigned short)(M0.z >> 16)))); \
        ACC4(g3, __half2float(__ushort_as_half((unsigned short)(M0.w >> 16)))); \
        ACC4(g4, __half2float(__ushort_as_half((unsigned short)(M1.x >> 16)))); \
        ACC4(g5, __half2float(__ushort_as_half((unsigned short)(M1.y >> 16)))); \
        ACC4(g6, __half2float(__ushort_as_half((unsigned short)(M1.z >> 16)))); \
        ACC4(g7, __half2float(__ushort_as_half((unsigned short)(M1.w >> 16)))); \
    }

__device__ __forceinline__ void node_body(
        int node, int eg, int li, uint4 m0, uint4 m1, int c, int flag, float bscal,
        const uint2* __restrict__ hv, uint2* __restrict__ ho,
        const float* __restrict__ bin, const unsigned* __restrict__ um2) {
    float a0 = 0.f, a1 = 0.f, a2 = 0.f, a3 = 0.f;
    GATHER8(m0, m1);
    if (c > 32) {                         // ~1e-4 of nodes; uniform branch
        const uint4* q2 = (const uint4*)(um2 + (size_t)node * 32) + eg * 2;
        uint4 n0 = q2[0], n1 = q2[1];
        GATHER8(n0, n1);
    }
    a0 += __shfl_xor(a0, 16); a1 += __shfl_xor(a1, 16);
    a2 += __shfl_xor(a2, 16); a3 += __shfl_xor(a3, 16);
    a0 += __shfl_xor(a0, 32); a1 += __shfl_xor(a1, 32);
    a2 += __shfl_xor(a2, 32); a3 += __shfl_xor(a3, 32);

    if (eg == 0) {
        float b0, b1, b2, b3;
        if (flag) {
            float4 bb = ((const float4*)bin)[node * 16 + li];
            b0 = bb.x; b1 = bb.y; b2 = bb.z; b3 = bb.w;
        } else {
            b0 = b1 = b2 = b3 = bscal;
        }
        float r0 = b0 + a0, r1 = b1 + a1, r2 = b2 + a2, r3 = b3 + a3;
        float u0 = (r0 < 0.f) ? r0 * LEAK : r0;
        float u1 = (r1 < 0.f) ? r1 * LEAK : r1;
        float u2 = (r2 < 0.f) ? r2 * LEAK : r2;
        float u3 = (r3 < 0.f) ? r3 * LEAK : r3;
        float v0 = (u0 > 0.5f) ? (1.0f - 0.25f / u0) : u0;
        float v1 = (u1 > 0.5f) ? (1.0f - 0.25f / u1) : u1;
        float v2 = (u2 > 0.5f) ? (1.0f - 0.25f / u2) : u2;
        float v3 = (u3 > 0.5f) ? (1.0f - 0.25f / u3) : u3;
        union { __half2 h; unsigned u; } p01, p23;
        p01.h = __halves2half2(__float2half(v0), __float2half(v1));
        p23.h = __halves2half2(__float2half(v2), __float2half(v3));
        uint2 st; st.x = p01.u; st.y = p23.u;
        ho[node * 16 + li] = st;
    }
}

// ---------------------------------------------------------------------------
// persistent kernel: all 150 iterations in one dispatch. Edge meta / counts /
// biases hoisted into registers once. Hand-rolled distributed grid barrier:
// 64 padded counters (16 blocks each, arrivals pipeline in parallel), block-0
// wave-0 collects, one `go` generation flag. One wbL2 release + one inv
// acquire per BLOCK per step. grid.sync() is never used (100us/step, round 3).
// ---------------------------------------------------------------------------
__global__ __launch_bounds__(NTHREADS, 4) void persistent_kernel(
        __half* __restrict__ h0, __half* __restrict__ h1,
        const float* __restrict__ bin, const float* __restrict__ biases,
        const unsigned* __restrict__ um, const unsigned* __restrict__ um2,
        const int* __restrict__ cnt, int* __restrict__ ctr, int* __restrict__ go) {
    int wave = (blockIdx.x << 2) | (threadIdx.x >> 6);
    int lane = threadIdx.x & 63;
    int eg = lane >> 4;
    int li = lane & 15;
    int nbase = __builtin_amdgcn_readfirstlane(wave * NPW);

    // hoist per-node constants for the whole run (static indexing: full unroll)
    uint4 ma[NPW], mb[NPW];
    int   cc[NPW], fl[NPW];
    float bs[NPW];
#pragma unroll
    for (int j = 0; j < NPW; j++) {
        int node = nbase + j;
        ma[j] = make_uint4(0u, 0u, 0u, 0u);
        mb[j] = make_uint4(0u, 0u, 0u, 0u);
        cc[j] = 0; fl[j] = 0; bs[j] = 0.f;
        if (node < N_NODES) {
            int cv = cnt[node];
            int c = cv & CNT_MASK;
            if (c > CAP) c = CAP;
            cc[j] = c; fl[j] = cv & FLAG_BIT; bs[j] = biases[node];
            const uint4* q = (const uint4*)(um + (size_t)node * 32) + eg * 2;
            ma[j] = q[0]; mb[j] = q[1];
        }
    }

    for (int t = 0; t < ITERS; t++) {
        const uint2* hv = (const uint2*)((t & 1) ? h1 : h0);
        uint2*       ho = (uint2*)((t & 1) ? h0 : h1);
#pragma unroll
        for (int j = 0; j < NPW; j++) {
            int node = nbase + j;
            if (node < N_NODES)
                node_body(node, eg, li, ma[j], mb[j], cc[j], fl[j], bs[j],
                          hv, ho, bin, um2);
        }
        if (t == ITERS - 1) break;

        // ---- device-wide barrier, generation t+1 ----
        __syncthreads();                       // drains all waves' stores (vmcnt)
        if (threadIdx.x == 0) {
            __threadfence();                   // wbL2: publish to coherent point
            AT_ADD(&ctr[(blockIdx.x & (CTRS - 1)) * CTR_STRIDE], 1);
        }
        if (blockIdx.x == 0) {
            if (threadIdx.x < CTRS) {
                int target = (t + 1) * (NBLOCKS / CTRS);
                while (AT_LD(&ctr[threadIdx.x * CTR_STRIDE]) < target)
                    __builtin_amdgcn_s_sleep(1);
            }
            __syncthreads();
            if (threadIdx.x == 0) AT_ST(go, t + 1);
        }
        if (threadIdx.x == 0) {
            while (AT_LD(go) < t + 1) __builtin_amdgcn_s_sleep(1);
            __threadfence();                   // inv: discard stale L1/L2
        }
        __syncthreads();
    }
}

// ---------------------------------------------------------------------------
// fallback: one iteration per launch (round-7 structure, same numerics)
// ---------------------------------------------------------------------------
__global__ __launch_bounds__(256) void step_kernel(
        const __half* __restrict__ h_in, __half* __restrict__ h_out,
        const float* __restrict__ bin, const float* __restrict__ biases,
        const unsigned* __restrict__ um, const unsigned* __restrict__ um2,
        const int* __restrict__ cnt) {
    int lane = threadIdx.x & 63;
    int node = __builtin_amdgcn_readfirstlane((blockIdx.x << 2) | (threadIdx.x >> 6));
    int eg = lane >> 4;
    int li = lane & 15;
    int cv = cnt[node];
    int c = cv & CNT_MASK;
    if (c > CAP) c = CAP;
    const uint4* q = (const uint4*)(um + (size_t)node * 32) + eg * 2;
    uint4 m0 = q[0], m1 = q[1];
    node_body(node, eg, li, m0, m1, c, cv & FLAG_BIT, biases[node],
              (const uint2*)h_in, (uint2*)h_out, bin, um2);
}

// ---------------------------------------------------------------------------
// output gather: out[b][o] = out_w[o] * h[out_idx[o]][b]
// ---------------------------------------------------------------------------
__global__ void output_kernel(const __half* __restrict__ h,
                              const int* __restrict__ out_idx,
                              const float* __restrict__ out_w,
                              float* __restrict__ out) {
    int o = threadIdx.x;
    int b = blockIdx.x;
    out[b * N_OUT + o] = out_w[o] * __half2float(h[out_idx[o] * BATCH + b]);
}

// ---------------------------------------------------------------------------
extern "C" void kernel_launch(void* const* d_in, const int* in_sizes, int n_in,
                              void* d_out, int out_size, void* d_ws, size_t ws_size,
                              hipStream_t stream) {
    const float* x      = (const float*)d_in[0];
    const float* in_w   = (const float*)d_in[1];
    const float* out_w  = (const float*)d_in[2];
    const float* rec_w  = (const float*)d_in[3];
    const float* biases = (const float*)d_in[4];
    const int*   rows   = (const int*)d_in[5];
    const int*   cols   = (const int*)d_in[6];
    const int*   in_idx = (const int*)d_in[7];
    const int*   oidx   = (const int*)d_in[8];
    float* out = (float*)d_out;

    char* ws = (char*)d_ws;
    __half*   h0  = (__half*)ws;   ws += (size_t)N_NODES * BATCH * 2;   // 2.56 MB
    __half*   h1  = (__half*)ws;   ws += (size_t)N_NODES * BATCH * 2;   // 2.56 MB
    float*    bin = (float*)ws;    ws += (size_t)N_NODES * BATCH * 4;   // 5.12 MB
    unsigned* um  = (unsigned*)ws; ws += (size_t)N_NODES * 32 * 4;      // 2.56 MB
    unsigned* um2 = (unsigned*)ws; ws += (size_t)N_NODES * 32 * 4;      // 2.56 MB
    int*      cnt = (int*)ws;      ws += (size_t)N_NODES * 4;           // 80 KB
    int*      bar = (int*)ws;      ws += (size_t)(CTRS + 1) * CTR_STRIDE * 4;
    int*      go  = bar + CTRS * CTR_STRIDE;

    setup_kernel<<<2048, 256, 0, stream>>>((uint2*)h0, cnt, um, um2, bar);
    input_scatter_kernel<<<N_IN, BATCH, 0, stream>>>(bin, x, in_w, in_idx,
                                                     biases, cnt);
    ell_build_kernel<<<(N_EDGES + 255) / 256, 256, 0, stream>>>(rows, cols, rec_w,
                                                                um, um2, cnt);

    void* args[] = { (void*)&h0, (void*)&h1, (void*)&bin, (void*)&biases,
                     (void*)&um, (void*)&um2, (void*)&cnt, (void*)&bar, (void*)&go };
    hipError_t ce = hipLaunchCooperativeKernel((void*)persistent_kernel,
                                               dim3(NBLOCKS), dim3(NTHREADS),
                                               args, 0, stream);
    if (ce != hipSuccess) {
        // fallback: 150 explicit launches (ITERS even -> final lands in h0)
        __half* hA = h0;
        __half* hB = h1;
        for (int t = 0; t < ITERS; t++) {
            step_kernel<<<N_NODES / 4, 256, 0, stream>>>(hA, hB, bin, biases,
                                                         um, um2, cnt);
            __half* tmp = hA; hA = hB; hB = tmp;
        }
    }

    // ITERS even -> final state in h0 on both paths
    output_kernel<<<BATCH, N_OUT, 0, stream>>>(h0, oidx, out_w, out);
}

// Round 9
// 6604.928 us; speedup vs baseline: 1.2180x; 1.2180x over previous
//
#include <hip/hip_runtime.h>
#include <hip/hip_fp16.h>

#define N_NODES 20000
#define N_EDGES 320000
#define BATCH   64
#define N_IN    128
#define N_OUT   256
#define CAP     64
#define ITERS   150
#define LEAK    0.01f

#define CNT_MASK 0x3FFFFFFF
#define FLAG_BIT (1 << 30)

#define NBLOCKS    1024
#define NTHREADS   256
#define NPW        40                // nodes per wave: ceil(20000 / (128*4))
#define CTRS       64                // distributed barrier counters
#define CTR_STRIDE 32                // 128 B apart

// MALL-coherent (cross-XCD-safe) accessors: agent scope bypasses L1/L2, is
// served by the memory-side Infinity Cache -> coherent by construction.
#define AT_LD(p)    __hip_atomic_load((p), __ATOMIC_RELAXED, __HIP_MEMORY_SCOPE_AGENT)
#define AT_ADD(p,v) __hip_atomic_fetch_add((p),(v),__ATOMIC_RELAXED,__HIP_MEMORY_SCOPE_AGENT)
#define AT_LD64(p)  __hip_atomic_load((unsigned long long*)(p), __ATOMIC_RELAXED, __HIP_MEMORY_SCOPE_AGENT)
#define AT_ST64(p,v) __hip_atomic_store((p),(v),__ATOMIC_RELAXED,__HIP_MEMORY_SCOPE_AGENT)

typedef unsigned long long ull;
typedef unsigned int uint;

// ---------------------------------------------------------------------------
// setup: hA = 0 (fp16 sliced state), cnt = 0, barrier counters = 0.
// (hB fully written at t=0; mslotT guarded by cnt; bin guarded by flag.)
// ---------------------------------------------------------------------------
__global__ void setup_kernel(ull* __restrict__ hA, int* __restrict__ cnt,
                             int* __restrict__ ctr) {
    int idx = blockIdx.x * blockDim.x + threadIdx.x;
    int stride = gridDim.x * blockDim.x;
    for (int i = idx; i < 8 * N_NODES * 2; i += stride) hA[i] = 0ull;
    for (int i = idx; i < N_NODES; i += stride) cnt[i] = 0;
    for (int i = idx; i < CTRS * CTR_STRIDE; i += stride) ctr[i] = 0;
}

// ---------------------------------------------------------------------------
// input scatter: bin[in_idx[i]][b] = bias + in_w[i]*x[b][i], last-wins.
// Flags the node (bit 30 of cnt) so steps read bin only for those rows.
// ---------------------------------------------------------------------------
__global__ void input_scatter_kernel(float* __restrict__ bin,
                                     const float* __restrict__ x,
                                     const float* __restrict__ in_w,
                                     const int* __restrict__ in_idx,
                                     const float* __restrict__ biases,
                                     int* __restrict__ cnt) {
    int i = blockIdx.x;
    int b = threadIdx.x;
    int node = in_idx[i];
    if (b == 0) atomicOr(&cnt[node], FLAG_BIT);
    for (int j = i + 1; j < N_IN; j++)
        if (in_idx[j] == node) return;
    bin[node * BATCH + b] = biases[node] + in_w[i] * x[b * N_IN + i];
}

// ---------------------------------------------------------------------------
// COO -> transposed ELL: mslotT[s][node] = (fp16(w) << 16) | u16(col).
// Transposed so lane(=node) meta reads are coalesced. No zero-init needed:
// every read is guarded by k < c.
// ---------------------------------------------------------------------------
__global__ void ell_build_kernel(const int* __restrict__ rows,
                                 const int* __restrict__ cols,
                                 const float* __restrict__ rec_w,
                                 uint* __restrict__ mslotT, int* __restrict__ cnt) {
    int e = blockIdx.x * blockDim.x + threadIdx.x;
    if (e >= N_EDGES) return;
    int r = rows[e];
    int s = atomicAdd(&cnt[r], 1) & CNT_MASK;
    if (s < CAP) {
        uint v = ((uint)__half_as_ushort(__float2half(rec_w[e])) << 16)
               | (uint)cols[e];
        mslotT[s * N_NODES + r] = v;
    }
}

// ---------------------------------------------------------------------------
// per-node body: lane owns one node end-to-end (no cross-lane reduce).
// h state sliced [slice][node][8 fp16]; gathers/stores are MALL-coherent
// atomics; 8-way unroll keeps 16 independent 8B gathers in flight.
// ---------------------------------------------------------------------------
__device__ __forceinline__ void node_pass(
        bool active, int node, int c, float4 bc0, float4 bc1,
        const uint* __restrict__ mslotT,
        const ull* hin_sl, ull* hout_sl) {
    float a[8];
#pragma unroll
    for (int j = 0; j < 8; j++) a[j] = 0.f;

    for (int k = 0; k < c; k += 8) {
        uint m[8];
        ull lo[8], hi[8];
#pragma unroll
        for (int j = 0; j < 8; j++) {
            m[j] = 0u;
            if (k + j < c) m[j] = mslotT[(k + j) * N_NODES + node];
        }
#pragma unroll
        for (int j = 0; j < 8; j++) {
            lo[j] = 0ull; hi[j] = 0ull;
            if (k + j < c) {
                const ull* p = hin_sl + ((size_t)(m[j] & 0xFFFFu) << 1);
                lo[j] = AT_LD64(p);
                hi[j] = AT_LD64(p + 1);
            }
        }
#pragma unroll
        for (int j = 0; j < 8; j++) {
            if (k + j < c) {
                float w = __half2float(__ushort_as_half((unsigned short)(m[j] >> 16)));
                union { uint u; __half2 h; } c0, c1, c2, c3;
                c0.u = (uint)lo[j];        c1.u = (uint)(lo[j] >> 32);
                c2.u = (uint)hi[j];        c3.u = (uint)(hi[j] >> 32);
                float2 f0 = __half22float2(c0.h), f1 = __half22float2(c1.h);
                float2 f2 = __half22float2(c2.h), f3 = __half22float2(c3.h);
                a[0] = fmaf(w, f0.x, a[0]); a[1] = fmaf(w, f0.y, a[1]);
                a[2] = fmaf(w, f1.x, a[2]); a[3] = fmaf(w, f1.y, a[3]);
                a[4] = fmaf(w, f2.x, a[4]); a[5] = fmaf(w, f2.y, a[5]);
                a[6] = fmaf(w, f3.x, a[6]); a[7] = fmaf(w, f3.y, a[7]);
            }
        }
    }

    if (active) {
        float b[8] = {bc0.x, bc0.y, bc0.z, bc0.w, bc1.x, bc1.y, bc1.z, bc1.w};
        unsigned short us[8];
#pragma unroll
        for (int j = 0; j < 8; j++) {
            float r = b[j] + a[j];
            float u = (r < 0.f) ? r * LEAK : r;
            float v = (u > 0.5f) ? (1.0f - 0.25f / u) : u;
            us[j] = __half_as_ushort(__float2half(v));
        }
        ull v0 = (ull)us[0] | ((ull)us[1] << 16) | ((ull)us[2] << 32) | ((ull)us[3] << 48);
        ull v1 = (ull)us[4] | ((ull)us[5] << 16) | ((ull)us[6] << 32) | ((ull)us[7] << 48);
        ull* q = hout_sl + ((size_t)node << 1);
        AT_ST64(q, v0);
        AT_ST64(q + 1, v1);
    }
}

// shared per-lane invariants
__device__ __forceinline__ void lane_consts(
        int bid, int tid, const int* __restrict__ cnt,
        const float* __restrict__ biases, const float* __restrict__ bin,
        int& g, int& node, bool& active, int& c, float4& bc0, float4& bc1) {
    int w = tid >> 6, lane = tid & 63;
    g = bid & 7;
    int rank = bid >> 3;
    int rw = rank * 4 + w;
    node = rw * NPW + lane;
    active = (lane < NPW) && (node < N_NODES);
    c = 0;
    int flag = 0;
    float bb = 0.f;
    if (active) {
        int cv = cnt[node];
        c = cv & CNT_MASK;
        if (c > CAP) c = CAP;
        flag = cv & FLAG_BIT;
        bb = biases[node];
    }
    bc0 = make_float4(bb, bb, bb, bb);
    bc1 = bc0;
    if (flag) {
        const float* bp = bin + (size_t)node * BATCH + g * 8;
        bc0 = make_float4(bp[0], bp[1], bp[2], bp[3]);
        bc1 = make_float4(bp[4], bp[5], bp[6], bp[7]);
    }
}

// ---------------------------------------------------------------------------
// persistent kernel: 150 iterations in one dispatch. NO fences, NO cache
// invalidation: h lives only at the MALL (agent-scope atomics), so the
// barrier is just counters. Release = __syncthreads (vmcnt drain) + add;
// acquire = observing the counters.
// ---------------------------------------------------------------------------
__global__ __launch_bounds__(NTHREADS, 4) void persistent_kernel(
        ull* hA, ull* hB,
        const float* __restrict__ bin, const float* __restrict__ biases,
        const uint* __restrict__ mslotT, const int* __restrict__ cnt,
        int* ctr) {
    int tid = threadIdx.x, bid = blockIdx.x;
    int w = tid >> 6, lane = tid & 63;
    int g, node, c; bool active; float4 bc0, bc1;
    lane_consts(bid, tid, cnt, biases, bin, g, node, active, c, bc0, bc1);

    ull* hA_sl = hA + ((size_t)g * N_NODES << 1);
    ull* hB_sl = hB + ((size_t)g * N_NODES << 1);

    for (int t = 0; t < ITERS; t++) {
        const ull* hin = (t & 1) ? hB_sl : hA_sl;
        ull*       ho  = (t & 1) ? hA_sl : hB_sl;
        node_pass(active, node, c, bc0, bc1, mslotT, hin, ho);
        if (t == ITERS - 1) break;

        __threadfence_block();            // vmcnt drain (stores reach MALL)
        __syncthreads();
        if (tid == 0) AT_ADD(&ctr[(bid & (CTRS - 1)) * CTR_STRIDE], 1);
        if (w == 0 && lane < CTRS) {
            int target = (t + 1) * (NBLOCKS / CTRS);
            while (AT_LD(&ctr[lane * CTR_STRIDE]) < target)
                __builtin_amdgcn_s_sleep(2);
        }
        __syncthreads();
    }
}

// ---------------------------------------------------------------------------
// fallback: one iteration per launch, same data structures / numerics
// ---------------------------------------------------------------------------
__global__ __launch_bounds__(NTHREADS) void step_kernel(
        const ull* hin, ull* hout,
        const float* __restrict__ bin, const float* __restrict__ biases,
        const uint* __restrict__ mslotT, const int* __restrict__ cnt) {
    int g, node, c; bool active; float4 bc0, bc1;
    lane_consts(blockIdx.x, threadIdx.x, cnt, biases, bin, g, node, active, c, bc0, bc1);
    node_pass(active, node, c, bc0, bc1, mslotT,
              hin + ((size_t)g * N_NODES << 1), hout + ((size_t)g * N_NODES << 1));
}

// ---------------------------------------------------------------------------
// output gather: out[b][o] = out_w[o] * h[out_idx[o]][b]
// h layout: [slice=b>>3][node][8 fp16]
// ---------------------------------------------------------------------------
__global__ void output_kernel(const __half* __restrict__ h,
                              const int* __restrict__ out_idx,
                              const float* __restrict__ out_w,
                              float* __restrict__ out) {
    int o = threadIdx.x;
    int b = blockIdx.x;
    int node = out_idx[o];
    float v = __half2float(h[((size_t)(b >> 3) * N_NODES + node) * 8 + (b & 7)]);
    out[b * N_OUT + o] = out_w[o] * v;
}

// ---------------------------------------------------------------------------
extern "C" void kernel_launch(void* const* d_in, const int* in_sizes, int n_in,
                              void* d_out, int out_size, void* d_ws, size_t ws_size,
                              hipStream_t stream) {
    const float* x      = (const float*)d_in[0];
    const float* in_w   = (const float*)d_in[1];
    const float* out_w  = (const float*)d_in[2];
    const float* rec_w  = (const float*)d_in[3];
    const float* biases = (const float*)d_in[4];
    const int*   rows   = (const int*)d_in[5];
    const int*   cols   = (const int*)d_in[6];
    const int*   in_idx = (const int*)d_in[7];
    const int*   oidx   = (const int*)d_in[8];
    float* out = (float*)d_out;

    char* ws = (char*)d_ws;
    ull*   hA     = (ull*)ws;   ws += (size_t)8 * N_NODES * 16;      // 2.56 MB
    ull*   hB     = (ull*)ws;   ws += (size_t)8 * N_NODES * 16;      // 2.56 MB
    float* bin    = (float*)ws; ws += (size_t)N_NODES * BATCH * 4;   // 5.12 MB
    uint*  mslotT = (uint*)ws;  ws += (size_t)CAP * N_NODES * 4;     // 5.12 MB
    int*   cnt    = (int*)ws;   ws += (size_t)N_NODES * 4;           // 80 KB
    int*   ctr    = (int*)ws;   ws += (size_t)CTRS * CTR_STRIDE * 4; // 8 KB

    setup_kernel<<<1024, 256, 0, stream>>>(hA, cnt, ctr);
    input_scatter_kernel<<<N_IN, BATCH, 0, stream>>>(bin, x, in_w, in_idx,
                                                     biases, cnt);
    ell_build_kernel<<<(N_EDGES + 255) / 256, 256, 0, stream>>>(rows, cols, rec_w,
                                                                mslotT, cnt);

    void* args[] = { (void*)&hA, (void*)&hB, (void*)&bin, (void*)&biases,
                     (void*)&mslotT, (void*)&cnt, (void*)&ctr };
    hipError_t ce = hipLaunchCooperativeKernel((void*)persistent_kernel,
                                               dim3(NBLOCKS), dim3(NTHREADS),
                                               args, 0, stream);
    if (ce != hipSuccess) {
        // fallback: 150 explicit launches (dispatch boundaries provide sync)
        ull* pa = hA;
        ull* pb = hB;
        for (int t = 0; t < ITERS; t++) {
            step_kernel<<<NBLOCKS, NTHREADS, 0, stream>>>(pa, pb, bin, biases,
                                                          mslotT, cnt);
            ull* tmp = pa; pa = pb; pb = tmp;
        }
    }

    // ITERS even -> final state in hA on both paths
    output_kernel<<<BATCH, N_OUT, 0, stream>>>((const __half*)hA, oidx, out_w, out);
}

// Round 10
// 3254.598 us; speedup vs baseline: 2.4718x; 2.0294x over previous
//
#include <hip/hip_runtime.h>
#include <hip/hip_fp16.h>

#define N_NODES 20000
#define N_EDGES 320000
#define BATCH   64
#define N_IN    128
#define N_OUT   256
#define CAP     64
#define ITERS   150
#define LEAK    0.01f

#define CNT_MASK 0x3FFFFFFF
#define FLAG_BIT (1 << 30)

#define NSLICE 32        // batch pairs; slice s owns batch elems {2s, 2s+1}
#define BPS    8         // blocks per slice
#define NPB    2500      // nodes per block (8 * 2500 = 20000)
#define NT     1024      // threads per block (16 waves)
#define NPT    3         // node slots per thread (ceil(2500/1024))
#define NBLK   (NSLICE * BPS)   // 256 blocks = 1 per CU
#define CTR_STRIDE 32    // ints -> 128 B between slice counters

typedef unsigned int uint;
typedef unsigned long long ull;

// MALL-coherent accessors (cross-XCD-safe; bypass L1/L2)
#define AT_LD32(p)   __hip_atomic_load((const uint*)(p), __ATOMIC_RELAXED, __HIP_MEMORY_SCOPE_AGENT)
#define AT_ST32(p,v) __hip_atomic_store((uint*)(p), (v), __ATOMIC_RELAXED, __HIP_MEMORY_SCOPE_AGENT)
#define AT_LD64(p)   __hip_atomic_load((const ull*)(p), __ATOMIC_RELAXED, __HIP_MEMORY_SCOPE_AGENT)

// ---------------------------------------------------------------------------
// setup: hGA = 0 (fallback's t=0 input), cnt = 0, slice counters = 0
// ---------------------------------------------------------------------------
__global__ void setup_kernel(uint* __restrict__ hGA, int* __restrict__ cnt,
                             int* __restrict__ ctr) {
    int idx = blockIdx.x * blockDim.x + threadIdx.x;
    int stride = gridDim.x * blockDim.x;
    for (int i = idx; i < NSLICE * N_NODES; i += stride) hGA[i] = 0u;
    for (int i = idx; i < N_NODES; i += stride) cnt[i] = 0;
    for (int i = idx; i < NSLICE * CTR_STRIDE; i += stride) ctr[i] = 0;
}

// ---------------------------------------------------------------------------
// input scatter: bin[in_idx[i]][b] = bias + in_w[i]*x[b][i], last-wins.
// Flags the node (bit 30 of cnt) so steps read bin only for those rows.
// ---------------------------------------------------------------------------
__global__ void input_scatter_kernel(float* __restrict__ bin,
                                     const float* __restrict__ x,
                                     const float* __restrict__ in_w,
                                     const int* __restrict__ in_idx,
                                     const float* __restrict__ biases,
                                     int* __restrict__ cnt) {
    int i = blockIdx.x;
    int b = threadIdx.x;
    int node = in_idx[i];
    if (b == 0) atomicOr(&cnt[node], FLAG_BIT);
    for (int j = i + 1; j < N_IN; j++)
        if (in_idx[j] == node) return;
    bin[node * BATCH + b] = biases[node] + in_w[i] * x[b * N_IN + i];
}

// ---------------------------------------------------------------------------
// COO -> transposed ELL: mslotT[s][node] = (fp16(w) << 16) | u16(col).
// Transposed so per-k meta reads coalesce across threads (node = tid-contig).
// All reads guarded by k < c, so no zero-init needed.
// ---------------------------------------------------------------------------
__global__ void ell_build_kernel(const int* __restrict__ rows,
                                 const int* __restrict__ cols,
                                 const float* __restrict__ rec_w,
                                 uint* __restrict__ mslotT, int* __restrict__ cnt) {
    int e = blockIdx.x * blockDim.x + threadIdx.x;
    if (e >= N_EDGES) return;
    int r = rows[e];
    int s = atomicAdd(&cnt[r], 1) & CNT_MASK;
    if (s < CAP)
        mslotT[(size_t)s * N_NODES + r] =
            ((uint)__half_as_ushort(__float2half(rec_w[e])) << 16) | (uint)cols[e];
}

// ---------------------------------------------------------------------------
// per-node SpMV + activation (2 batch elems packed in u32 of 2 fp16).
// Gathers hit only the block-local LDS mirror.
// ---------------------------------------------------------------------------
__device__ __forceinline__ uint compute_node(int n, int c, float b0, float b1,
                                             const uint* __restrict__ mslotT,
                                             const uint* __restrict__ lds_h) {
    float a0 = 0.f, a1 = 0.f;
    for (int k = 0; k < c; k++) {
        uint m  = mslotT[(size_t)k * N_NODES + n];
        uint hv = lds_h[m & 0xFFFFu];
        float w = __half2float(__ushort_as_half((unsigned short)(m >> 16)));
        union { uint u; __half2 h; } cv; cv.u = hv;
        float2 f = __half22float2(cv.h);
        a0 = fmaf(w, f.x, a0);
        a1 = fmaf(w, f.y, a1);
    }
    float r0 = b0 + a0, r1 = b1 + a1;
    float u0 = (r0 < 0.f) ? r0 * LEAK : r0;
    float u1 = (r1 < 0.f) ? r1 * LEAK : r1;
    float v0 = (u0 > 0.5f) ? (1.0f - 0.25f / u0) : u0;
    float v1 = (u1 > 0.5f) ? (1.0f - 0.25f / u1) : u1;
    union { __half2 h; uint u; } p;
    p.h = __halves2half2(__float2half(v0), __float2half(v1));
    return p.u;
}

// hoist step-invariant per-node constants into registers
__device__ __forceinline__ void hoist_consts(
        int nbase, int tid, int s, const int* __restrict__ cnt,
        const float* __restrict__ bin, const float* __restrict__ biases,
        int* myn, int* myc, float* mb0, float* mb1, bool* ma) {
#pragma unroll
    for (int j = 0; j < NPT; j++) {
        int r = tid + j * NT;
        ma[j] = (r < NPB);
        int n = nbase + (ma[j] ? r : 0);
        myn[j] = n; myc[j] = 0; mb0[j] = 0.f; mb1[j] = 0.f;
        if (ma[j]) {
            int cv = cnt[n];
            int c = cv & CNT_MASK;
            if (c > CAP) c = CAP;
            myc[j] = c;
            if (cv & FLAG_BIT) {
                mb0[j] = bin[(size_t)n * BATCH + 2 * s];
                mb1[j] = bin[(size_t)n * BATCH + 2 * s + 1];
            } else {
                float bb = biases[n];
                mb0[j] = bb; mb1[j] = bb;
            }
        }
    }
}

// ---------------------------------------------------------------------------
// persistent kernel: 150 iterations in one dispatch. Per-slice independence:
// 8 blocks share a slice; gathers are LDS-local; exchange via MALL double
// buffer; barrier = one monotone counter per slice (8 arrivals, 8 pollers,
// disjoint 128B lines -> no cross-slice coupling, no fences, no L2 reliance).
// ---------------------------------------------------------------------------
__global__ __launch_bounds__(NT) void persistent_kernel(
        uint* hGA, uint* hGB,
        const float* __restrict__ bin, const float* __restrict__ biases,
        const uint* __restrict__ mslotT, const int* __restrict__ cnt,
        int* ctr) {
    extern __shared__ uint lds_h[];          // N_NODES u32 = 80 KB slice mirror
    int bid = blockIdx.x;
    int s   = bid >> 3;                      // slice 0..31
    int sub = bid & 7;                       // sub-block within slice
    int tid = threadIdx.x;
    int nbase = sub * NPB;

    int myn[NPT], myc[NPT]; float mb0[NPT], mb1[NPT]; bool ma[NPT];
    hoist_consts(nbase, tid, s, cnt, bin, biases, myn, myc, mb0, mb1, ma);

    for (int i = tid; i < N_NODES; i += NT) lds_h[i] = 0u;   // h_{-1} = 0
    __syncthreads();

    uint* hA_s = hGA + (size_t)s * N_NODES;
    uint* hB_s = hGB + (size_t)s * N_NODES;
    int* myctr = &ctr[s * CTR_STRIDE];

    for (int t = 0; t < ITERS; t++) {
        uint* hout = (t & 1) ? hB_s : hA_s;
        // phase A: compute owned nodes from LDS mirror, publish to MALL
#pragma unroll
        for (int j = 0; j < NPT; j++) {
            if (ma[j]) {
                uint v = compute_node(myn[j], myc[j], mb0[j], mb1[j], mslotT, lds_h);
                AT_ST32(&hout[myn[j]], v);
            }
        }
        if (t == ITERS - 1) break;

        __syncthreads();                     // all lds reads done, stores drained
        if (tid == 0) {
            __hip_atomic_fetch_add(myctr, 1, __ATOMIC_RELEASE, __HIP_MEMORY_SCOPE_AGENT);
            int target = BPS * (t + 1);
            while (__hip_atomic_load(myctr, __ATOMIC_ACQUIRE, __HIP_MEMORY_SCOPE_AGENT) < target)
                __builtin_amdgcn_s_sleep(8);
        }
        __syncthreads();
        // phase C: refresh LDS mirror from MALL (coalesced b64)
        const ull* src = (const ull*)hout;
        ull* dst = (ull*)lds_h;
        for (int i = tid; i < N_NODES / 2; i += NT) dst[i] = AT_LD64(&src[i]);
        __syncthreads();
    }
}

// ---------------------------------------------------------------------------
// fallback: same structure, one step per launch (dispatch boundary = sync)
// ---------------------------------------------------------------------------
__global__ __launch_bounds__(NT) void step_kernel(
        const uint* __restrict__ hprev, uint* __restrict__ hnext,
        const float* __restrict__ bin, const float* __restrict__ biases,
        const uint* __restrict__ mslotT, const int* __restrict__ cnt) {
    extern __shared__ uint lds_h[];
    int bid = blockIdx.x;
    int s   = bid >> 3;
    int sub = bid & 7;
    int tid = threadIdx.x;
    int nbase = sub * NPB;

    int myn[NPT], myc[NPT]; float mb0[NPT], mb1[NPT]; bool ma[NPT];
    hoist_consts(nbase, tid, s, cnt, bin, biases, myn, myc, mb0, mb1, ma);

    const uint* hp = hprev + (size_t)s * N_NODES;
    for (int i = tid; i < N_NODES; i += NT) lds_h[i] = hp[i];
    __syncthreads();

    uint* ho = hnext + (size_t)s * N_NODES;
#pragma unroll
    for (int j = 0; j < NPT; j++) {
        if (ma[j]) {
            uint v = compute_node(myn[j], myc[j], mb0[j], mb1[j], mslotT, lds_h);
            ho[myn[j]] = v;
        }
    }
}

// ---------------------------------------------------------------------------
// output gather: out[b][o] = out_w[o] * h[out_idx[o]][b]
// hfinal layout [slice][node] u32 (2 fp16); b -> slice b>>1, half b&1
// ---------------------------------------------------------------------------
__global__ void output_kernel(const uint* __restrict__ hfinal,
                              const int* __restrict__ out_idx,
                              const float* __restrict__ out_w,
                              float* __restrict__ out) {
    int o = threadIdx.x;
    int b = blockIdx.x;
    uint v = hfinal[(size_t)(b >> 1) * N_NODES + out_idx[o]];
    unsigned short h = (b & 1) ? (unsigned short)(v >> 16) : (unsigned short)(v & 0xFFFF);
    out[b * N_OUT + o] = out_w[o] * __half2float(__ushort_as_half(h));
}

// ---------------------------------------------------------------------------
extern "C" void kernel_launch(void* const* d_in, const int* in_sizes, int n_in,
                              void* d_out, int out_size, void* d_ws, size_t ws_size,
                              hipStream_t stream) {
    const float* x      = (const float*)d_in[0];
    const float* in_w   = (const float*)d_in[1];
    const float* out_w  = (const float*)d_in[2];
    const float* rec_w  = (const float*)d_in[3];
    const float* biases = (const float*)d_in[4];
    const int*   rows   = (const int*)d_in[5];
    const int*   cols   = (const int*)d_in[6];
    const int*   in_idx = (const int*)d_in[7];
    const int*   oidx   = (const int*)d_in[8];
    float* out = (float*)d_out;

    char* ws = (char*)d_ws;
    uint*  hGA    = (uint*)ws;  ws += (size_t)NSLICE * N_NODES * 4;   // 2.56 MB
    uint*  hGB    = (uint*)ws;  ws += (size_t)NSLICE * N_NODES * 4;   // 2.56 MB
    float* bin    = (float*)ws; ws += (size_t)N_NODES * BATCH * 4;    // 5.12 MB
    uint*  mslotT = (uint*)ws;  ws += (size_t)CAP * N_NODES * 4;      // 5.12 MB
    int*   cnt    = (int*)ws;   ws += (size_t)N_NODES * 4;            // 80 KB
    int*   ctr    = (int*)ws;   ws += (size_t)NSLICE * CTR_STRIDE * 4;

    const int shmem = N_NODES * 4;   // 80 KB dynamic LDS
    hipFuncSetAttribute((const void*)persistent_kernel,
                        hipFuncAttributeMaxDynamicSharedMemorySize, shmem);
    hipFuncSetAttribute((const void*)step_kernel,
                        hipFuncAttributeMaxDynamicSharedMemorySize, shmem);

    setup_kernel<<<1024, 256, 0, stream>>>(hGA, cnt, ctr);
    input_scatter_kernel<<<N_IN, BATCH, 0, stream>>>(bin, x, in_w, in_idx,
                                                     biases, cnt);
    ell_build_kernel<<<(N_EDGES + 255) / 256, 256, 0, stream>>>(rows, cols, rec_w,
                                                                mslotT, cnt);

    void* args[] = { (void*)&hGA, (void*)&hGB, (void*)&bin, (void*)&biases,
                     (void*)&mslotT, (void*)&cnt, (void*)&ctr };
    hipError_t ce = hipLaunchCooperativeKernel((void*)persistent_kernel,
                                               dim3(NBLK), dim3(NT),
                                               args, shmem, stream);
    const uint* hfinal;
    if (ce == hipSuccess) {
        // t=149 (odd) wrote hGB
        hfinal = hGB;
    } else {
        // fallback: 150 launches; t=0 reads hGA (zeroed), writes hGB, swap.
        // 150 launches -> final write lands in hGB.
        uint* pa = hGA;
        uint* pb = hGB;
        for (int t = 0; t < ITERS; t++) {
            step_kernel<<<NBLK, NT, shmem, stream>>>(pa, pb, bin, biases,
                                                     mslotT, cnt);
            uint* tmp = pa; pa = pb; pb = tmp;
        }
        hfinal = pa;   // after even # of swaps, pa points at last-written buf? 
        // pa/pb swap after each launch: launch t writes pb(before swap).
        // After 150 iterations (even), last write was to the buffer now in pa.
    }

    output_kernel<<<BATCH, N_OUT, 0, stream>>>(hfinal, oidx, out_w, out);
}

// Round 11
// 1921.114 us; speedup vs baseline: 4.1876x; 1.6941x over previous
//
#include <hip/hip_runtime.h>
#include <hip/hip_fp16.h>

#define N_NODES 20000
#define N_EDGES 320000
#define BATCH   64
#define N_IN    128
#define N_OUT   256
#define CAP     64
#define ITERS   150
#define LEAK    0.01f

#define CNT_MASK 0x3FFFFFFF
#define FLAG_BIT (1 << 30)

#define NSLICE 32        // batch pairs; slice s owns batch elems {2s, 2s+1}
#define BPS    8         // blocks per slice
#define NPB    2500      // nodes per block (8 * 2500 = 20000)
#define NT     1024      // threads per block (16 waves)
#define NBLK   (NSLICE * BPS)   // 256 blocks = 1 per CU
#define CTR_STRIDE 32    // ints -> 128 B between slice counters

typedef unsigned int uint;
typedef unsigned long long ull;

// MALL-coherent accessors: RELAXED ONLY. Agent-scope relaxed atomics bypass
// L1/L2 and are served by the memory-side Infinity Cache (coherent by
// construction). NO acquire/release anywhere: those compile to whole-L2
// inv/wb on gfx950 (round 8/10 disease). Ordering comes from __syncthreads'
// vmcnt drain + MALL serialization.
#define AT_LD32(p)   __hip_atomic_load((const uint*)(p), __ATOMIC_RELAXED, __HIP_MEMORY_SCOPE_AGENT)
#define AT_ST32(p,v) __hip_atomic_store((uint*)(p), (v), __ATOMIC_RELAXED, __HIP_MEMORY_SCOPE_AGENT)
#define AT_LD64(p)   __hip_atomic_load((const ull*)(p), __ATOMIC_RELAXED, __HIP_MEMORY_SCOPE_AGENT)
#define AT_LDI(p)    __hip_atomic_load((const int*)(p), __ATOMIC_RELAXED, __HIP_MEMORY_SCOPE_AGENT)
#define AT_ADDI(p,v) __hip_atomic_fetch_add((int*)(p), (v), __ATOMIC_RELAXED, __HIP_MEMORY_SCOPE_AGENT)

// ---------------------------------------------------------------------------
// setup: hGA = 0, cnt = 0, ctr = 0, mslotT = 0 (zero slots -> col 0, w 0:
// over-run reads in the unrolled loop are harmless broadcasts)
// ---------------------------------------------------------------------------
__global__ void setup_kernel(uint* __restrict__ hGA, int* __restrict__ cnt,
                             int* __restrict__ ctr, uint* __restrict__ mslotT) {
    int idx = blockIdx.x * blockDim.x + threadIdx.x;
    int stride = gridDim.x * blockDim.x;
    for (int i = idx; i < NSLICE * N_NODES; i += stride) hGA[i] = 0u;
    for (int i = idx; i < N_NODES; i += stride) cnt[i] = 0;
    for (int i = idx; i < NSLICE * CTR_STRIDE; i += stride) ctr[i] = 0;
    for (size_t i = idx; i < (size_t)CAP * N_NODES; i += stride) mslotT[i] = 0u;
}

// ---------------------------------------------------------------------------
// input scatter: bin[in_idx[i]][b] = bias + in_w[i]*x[b][i], last-wins.
// Flags the node (bit 30 of cnt) so steps read bin only for those rows.
// ---------------------------------------------------------------------------
__global__ void input_scatter_kernel(float* __restrict__ bin,
                                     const float* __restrict__ x,
                                     const float* __restrict__ in_w,
                                     const int* __restrict__ in_idx,
                                     const float* __restrict__ biases,
                                     int* __restrict__ cnt) {
    int i = blockIdx.x;
    int b = threadIdx.x;
    int node = in_idx[i];
    if (b == 0) atomicOr(&cnt[node], FLAG_BIT);
    for (int j = i + 1; j < N_IN; j++)
        if (in_idx[j] == node) return;
    bin[node * BATCH + b] = biases[node] + in_w[i] * x[b * N_IN + i];
}

// ---------------------------------------------------------------------------
// COO -> transposed ELL: mslotT[s][node] = (fp16(w) << 16) | u16(col).
// ---------------------------------------------------------------------------
__global__ void ell_build_kernel(const int* __restrict__ rows,
                                 const int* __restrict__ cols,
                                 const float* __restrict__ rec_w,
                                 uint* __restrict__ mslotT, int* __restrict__ cnt) {
    int e = blockIdx.x * blockDim.x + threadIdx.x;
    if (e >= N_EDGES) return;
    int r = rows[e];
    int s = atomicAdd(&cnt[r], 1) & CNT_MASK;
    if (s < CAP)
        mslotT[(size_t)s * N_NODES + r] =
            ((uint)__half_as_ushort(__float2half(rec_w[e])) << 16) | (uint)cols[e];
}

// epilogue: bias + acc -> activation -> packed 2xfp16
__device__ __forceinline__ uint finish_node(float a0, float a1, float b0, float b1) {
    float r0 = b0 + a0, r1 = b1 + a1;
    float u0 = (r0 < 0.f) ? r0 * LEAK : r0;
    float u1 = (r1 < 0.f) ? r1 * LEAK : r1;
    float v0 = (u0 > 0.5f) ? (1.0f - 0.25f / u0) : u0;
    float v1 = (u1 > 0.5f) ? (1.0f - 0.25f / u1) : u1;
    union { __half2 h; uint u; } p;
    p.h = __halves2half2(__float2half(v0), __float2half(v1));
    return p.u;
}

#define EDGE(m, A0, A1)                                                        \
    {                                                                          \
        uint hv = lds_h[(m) & 0xFFFFu];                                        \
        float w = __half2float(__ushort_as_half((unsigned short)((m) >> 16))); \
        union { uint u; __half2 h; } cu; cu.u = hv;                            \
        float2 f = __half22float2(cu.h);                                       \
        A0 = fmaf(w, f.x, A0); A1 = fmaf(w, f.y, A1);                          \
    }

// interleaved 3-node edge accumulation: 6 independent meta->LDS chains in
// flight (k unroll x2, 3 node streams). Zero meta slots are free broadcasts.
__device__ __forceinline__ void compute3(
        const int* myn, const int* myc, const uint* __restrict__ mslotT,
        const uint* __restrict__ lds_h, float* acc0, float* acc1) {
    int kmax = myc[0];
    if (myc[1] > kmax) kmax = myc[1];
    if (myc[2] > kmax) kmax = myc[2];
    const uint* p0 = mslotT + myn[0];
    const uint* p1 = mslotT + myn[1];
    const uint* p2 = mslotT + myn[2];
    float a00 = 0.f, a01 = 0.f, a10 = 0.f, a11 = 0.f, a20 = 0.f, a21 = 0.f;
    for (int k = 0; k < kmax; k += 2) {
        size_t o0 = (size_t)k * N_NODES, o1 = o0 + N_NODES;
        uint m00 = p0[o0], m01 = p0[o1];
        uint m10 = p1[o0], m11 = p1[o1];
        uint m20 = p2[o0], m21 = p2[o1];
        EDGE(m00, a00, a01); EDGE(m10, a10, a11); EDGE(m20, a20, a21);
        EDGE(m01, a00, a01); EDGE(m11, a10, a11); EDGE(m21, a20, a21);
    }
    acc0[0] = a00; acc1[0] = a01;
    acc0[1] = a10; acc1[1] = a11;
    acc0[2] = a20; acc1[2] = a21;
}

// hoist step-invariant per-node constants into registers
__device__ __forceinline__ void hoist_consts(
        int nbase, int tid, int s, const int* __restrict__ cnt,
        const float* __restrict__ bin, const float* __restrict__ biases,
        int* myn, int* myc, float* mb0, float* mb1, bool* ma) {
#pragma unroll
    for (int j = 0; j < 3; j++) {
        int r = tid + j * NT;
        ma[j] = (r < NPB);
        int n = nbase + (ma[j] ? r : 0);
        myn[j] = n; myc[j] = 0; mb0[j] = 0.f; mb1[j] = 0.f;
        if (ma[j]) {
            int cv = cnt[n];
            int c = cv & CNT_MASK;
            if (c > CAP) c = CAP;
            myc[j] = c;
            if (cv & FLAG_BIT) {
                mb0[j] = bin[(size_t)n * BATCH + 2 * s];
                mb1[j] = bin[(size_t)n * BATCH + 2 * s + 1];
            } else {
                float bb = biases[n];
                mb0[j] = bb; mb1[j] = bb;
            }
        }
    }
}

// ---------------------------------------------------------------------------
// persistent kernel: 150 iterations, one dispatch. Slice-private 8-block
// barrier on a MALL counter (relaxed only). LDS holds the full slice state;
// own nodes are written back to LDS from registers (overlapping the barrier),
// refresh pulls only the 17500 non-owned nodes from the MALL double buffer.
// ---------------------------------------------------------------------------
__global__ __launch_bounds__(NT) void persistent_kernel(
        uint* hGA, uint* hGB,
        const float* __restrict__ bin, const float* __restrict__ biases,
        const uint* __restrict__ mslotT, const int* __restrict__ cnt,
        int* ctr) {
    extern __shared__ uint lds_h[];          // N_NODES u32 = 80 KB slice mirror
    int bid = blockIdx.x;
    int s   = bid >> 3;
    int sub = bid & 7;
    int tid = threadIdx.x;
    int nbase = sub * NPB;

    int myn[3], myc[3]; float mb0[3], mb1[3]; bool ma[3];
    hoist_consts(nbase, tid, s, cnt, bin, biases, myn, myc, mb0, mb1, ma);

    for (int i = tid; i < N_NODES; i += NT) lds_h[i] = 0u;   // h_{-1} = 0
    __syncthreads();

    uint* hA_s = hGA + (size_t)s * N_NODES;
    uint* hB_s = hGB + (size_t)s * N_NODES;
    int* myctr = &ctr[s * CTR_STRIDE];
    const int lo = nbase >> 1, hi2 = (nbase + NPB) >> 1;   // own u64 range

    for (int t = 0; t < ITERS; t++) {
        uint* hout = (t & 1) ? hB_s : hA_s;

        float a0[3], a1[3];
        compute3(myn, myc, mslotT, lds_h, a0, a1);
        uint v[3];
#pragma unroll
        for (int j = 0; j < 3; j++) {
            v[j] = finish_node(a0[j], a1[j], mb0[j], mb1[j]);
            if (ma[j]) AT_ST32(&hout[myn[j]], v[j]);
        }
        if (t == ITERS - 1) break;

        __syncthreads();                  // all LDS reads done, stores drained
        // own nodes: update LDS straight from registers (overlaps barrier)
#pragma unroll
        for (int j = 0; j < 3; j++)
            if (ma[j]) lds_h[myn[j]] = v[j];
        if (tid == 0) {
            AT_ADDI(myctr, 1);
            int target = BPS * (t + 1);
            while (AT_LDI(myctr) < target) __builtin_amdgcn_s_sleep(8);
        }
        __syncthreads();
        // refresh non-owned nodes from the MALL double buffer (u64 coalesced)
        const ull* src = (const ull*)hout;
        ull* dst = (ull*)lds_h;
        for (int i = tid; i < N_NODES / 2; i += NT)
            if (i < lo || i >= hi2) dst[i] = AT_LD64(&src[i]);
        __syncthreads();
    }
}

// ---------------------------------------------------------------------------
// fallback: same structure, one step per launch (dispatch boundary = sync)
// ---------------------------------------------------------------------------
__global__ __launch_bounds__(NT) void step_kernel(
        const uint* __restrict__ hprev, uint* __restrict__ hnext,
        const float* __restrict__ bin, const float* __restrict__ biases,
        const uint* __restrict__ mslotT, const int* __restrict__ cnt) {
    extern __shared__ uint lds_h[];
    int bid = blockIdx.x;
    int s   = bid >> 3;
    int sub = bid & 7;
    int tid = threadIdx.x;
    int nbase = sub * NPB;

    int myn[3], myc[3]; float mb0[3], mb1[3]; bool ma[3];
    hoist_consts(nbase, tid, s, cnt, bin, biases, myn, myc, mb0, mb1, ma);

    const uint* hp = hprev + (size_t)s * N_NODES;
    for (int i = tid; i < N_NODES; i += NT) lds_h[i] = hp[i];
    __syncthreads();

    float a0[3], a1[3];
    compute3(myn, myc, mslotT, lds_h, a0, a1);
    uint* ho = hnext + (size_t)s * N_NODES;
#pragma unroll
    for (int j = 0; j < 3; j++)
        if (ma[j]) ho[myn[j]] = finish_node(a0[j], a1[j], mb0[j], mb1[j]);
}

// ---------------------------------------------------------------------------
// output gather: out[b][o] = out_w[o] * h[out_idx[o]][b]
// hfinal layout [slice][node] u32 (2 fp16); b -> slice b>>1, half b&1
// ---------------------------------------------------------------------------
__global__ void output_kernel(const uint* __restrict__ hfinal,
                              const int* __restrict__ out_idx,
                              const float* __restrict__ out_w,
                              float* __restrict__ out) {
    int o = threadIdx.x;
    int b = blockIdx.x;
    uint v = hfinal[(size_t)(b >> 1) * N_NODES + out_idx[o]];
    unsigned short h = (b & 1) ? (unsigned short)(v >> 16) : (unsigned short)(v & 0xFFFF);
    out[b * N_OUT + o] = out_w[o] * __half2float(__ushort_as_half(h));
}

// ---------------------------------------------------------------------------
extern "C" void kernel_launch(void* const* d_in, const int* in_sizes, int n_in,
                              void* d_out, int out_size, void* d_ws, size_t ws_size,
                              hipStream_t stream) {
    const float* x      = (const float*)d_in[0];
    const float* in_w   = (const float*)d_in[1];
    const float* out_w  = (const float*)d_in[2];
    const float* rec_w  = (const float*)d_in[3];
    const float* biases = (const float*)d_in[4];
    const int*   rows   = (const int*)d_in[5];
    const int*   cols   = (const int*)d_in[6];
    const int*   in_idx = (const int*)d_in[7];
    const int*   oidx   = (const int*)d_in[8];
    float* out = (float*)d_out;

    char* ws = (char*)d_ws;
    uint*  hGA    = (uint*)ws;  ws += (size_t)NSLICE * N_NODES * 4;   // 2.56 MB
    uint*  hGB    = (uint*)ws;  ws += (size_t)NSLICE * N_NODES * 4;   // 2.56 MB
    float* bin    = (float*)ws; ws += (size_t)N_NODES * BATCH * 4;    // 5.12 MB
    uint*  mslotT = (uint*)ws;  ws += (size_t)CAP * N_NODES * 4;      // 5.12 MB
    int*   cnt    = (int*)ws;   ws += (size_t)N_NODES * 4;            // 80 KB
    int*   ctr    = (int*)ws;   ws += (size_t)NSLICE * CTR_STRIDE * 4;

    const int shmem = N_NODES * 4;   // 80 KB dynamic LDS
    hipFuncSetAttribute((const void*)persistent_kernel,
                        hipFuncAttributeMaxDynamicSharedMemorySize, shmem);
    hipFuncSetAttribute((const void*)step_kernel,
                        hipFuncAttributeMaxDynamicSharedMemorySize, shmem);

    setup_kernel<<<2048, 256, 0, stream>>>(hGA, cnt, ctr, mslotT);
    input_scatter_kernel<<<N_IN, BATCH, 0, stream>>>(bin, x, in_w, in_idx,
                                                     biases, cnt);
    ell_build_kernel<<<(N_EDGES + 255) / 256, 256, 0, stream>>>(rows, cols, rec_w,
                                                                mslotT, cnt);

    void* args[] = { (void*)&hGA, (void*)&hGB, (void*)&bin, (void*)&biases,
                     (void*)&mslotT, (void*)&cnt, (void*)&ctr };
    hipError_t ce = hipLaunchCooperativeKernel((void*)persistent_kernel,
                                               dim3(NBLK), dim3(NT),
                                               args, shmem, stream);
    const uint* hfinal;
    if (ce == hipSuccess) {
        hfinal = hGB;                 // t=149 (odd) wrote hGB
    } else {
        // fallback: 150 launches; launch t reads pa, writes pb, swap.
        uint* pa = hGA;
        uint* pb = hGB;
        for (int t = 0; t < ITERS; t++) {
            step_kernel<<<NBLK, NT, shmem, stream>>>(pa, pb, bin, biases,
                                                     mslotT, cnt);
            uint* tmp = pa; pa = pb; pb = tmp;
        }
        hfinal = pa;                  // last write landed in the buffer now in pa
    }

    output_kernel<<<BATCH, N_OUT, 0, stream>>>(hfinal, oidx, out_w, out);
}